// Round 1
// baseline (443.035 us; speedup 1.0000x reference)
//
#include <hip/hip_runtime.h>

#define N_NODES 2048
#define N_FEAT  512
#define M_CHEB  10
#define Q_QUAD  64
#define KMAX    128          // max nnz per row of L_hat (expected ~32, tail-safe)
#define HK_THR  1e-5f
#define PI_F    3.14159265358979323846f

// ---------------------------------------------------------------------------
// Kernel 1: per-node Chebyshev coefficients c[i,k], k=0..M
// c[i,k] = (2/Q) * sum_q exp(-exp(t_i)*lam_q) * cos(k*theta_q);  c[:,0] *= 0.5
// ---------------------------------------------------------------------------
__global__ __launch_bounds__(256) void coeff_kernel(const float* __restrict__ t,
                                                    const float* __restrict__ eigmax,
                                                    float* __restrict__ cc) {
    int i = blockIdx.x * 256 + threadIdx.x;
    if (i >= N_NODES) return;
    float s  = expf(t[i]);
    float em = eigmax[0];
    float acc[M_CHEB + 1];
#pragma unroll
    for (int k = 0; k <= M_CHEB; ++k) acc[k] = 0.0f;
    for (int q = 0; q < Q_QUAD; ++q) {
        float th  = PI_F * ((float)q + 0.5f) / (float)Q_QUAD;
        float lam = em * 0.5f * (cosf(th) + 1.0f);
        float w   = expf(-s * lam);
#pragma unroll
        for (int k = 0; k <= M_CHEB; ++k) acc[k] += w * cosf((float)k * th);
    }
#pragma unroll
    for (int k = 0; k <= M_CHEB; ++k) {
        float v = acc[k] * (2.0f / (float)Q_QUAD);
        if (k == 0) v *= 0.5f;
        cc[i * (M_CHEB + 1) + k] = v;
    }
}

// ---------------------------------------------------------------------------
// Kernel 2: build CSR-ish (fixed-width) sparse rows of L_hat = (2/eig)*P - I
// Diagonal of P_n is exactly 1, so diag of L_hat is exactly 0 when eig==2 and
// falls out naturally via the v != 0 test (generic for any eig).
// ---------------------------------------------------------------------------
__global__ __launch_bounds__(256) void csr_kernel(const float* __restrict__ P,
                                                  const float* __restrict__ eigmax,
                                                  int* __restrict__ cols,
                                                  float* __restrict__ vals,
                                                  int* __restrict__ lens) {
    int row = blockIdx.x;
    __shared__ int cnt;
    if (threadIdx.x == 0) cnt = 0;
    __syncthreads();
    float s2 = 2.0f / eigmax[0];
    for (int j = threadIdx.x; j < N_NODES; j += 256) {
        float v = s2 * P[(size_t)row * N_NODES + j] - (j == row ? 1.0f : 0.0f);
        if (v != 0.0f) {
            int p = atomicAdd(&cnt, 1);
            if (p < KMAX) {
                cols[row * KMAX + p] = j;
                vals[row * KMAX + p] = v;
            }
        }
    }
    __syncthreads();
    if (threadIdx.x == 0) lens[row] = min(cnt, KMAX);
}

// ---------------------------------------------------------------------------
// Kernel 3: init T0 = I, T1 = L_hat, H = c0*I + c1*L_hat (dense, 256-col blocks)
// grid = (8, 2048), block = 64 (one wave), float4 per lane.
// ---------------------------------------------------------------------------
__global__ __launch_bounds__(64) void init_kernel(const float* __restrict__ P,
                                                  const float* __restrict__ eigmax,
                                                  const float* __restrict__ cc,
                                                  float* __restrict__ T0,
                                                  float* __restrict__ T1,
                                                  float* __restrict__ H) {
    int row = blockIdx.y;
    int col = blockIdx.x * 256 + threadIdx.x * 4;
    float s2 = 2.0f / eigmax[0];
    float c0 = cc[row * (M_CHEB + 1) + 0];
    float c1 = cc[row * (M_CHEB + 1) + 1];
    size_t off = (size_t)row * N_NODES + col;
    float4 p = *(const float4*)(P + off);
    float4 e;
    e.x = (col + 0 == row) ? 1.0f : 0.0f;
    e.y = (col + 1 == row) ? 1.0f : 0.0f;
    e.z = (col + 2 == row) ? 1.0f : 0.0f;
    e.w = (col + 3 == row) ? 1.0f : 0.0f;
    float4 l;
    l.x = s2 * p.x - e.x;
    l.y = s2 * p.y - e.y;
    l.z = s2 * p.z - e.z;
    l.w = s2 * p.w - e.w;
    *(float4*)(T0 + off) = e;
    *(float4*)(T1 + off) = l;
    float4 h;
    h.x = c0 * e.x + c1 * l.x;
    h.y = c0 * e.y + c1 * l.y;
    h.z = c0 * e.z + c1 * l.z;
    h.w = c0 * e.w + c1 * l.w;
    *(float4*)(H + off) = h;
}

// ---------------------------------------------------------------------------
// Kernel 4 (x9): one Chebyshev step.
//   Tnew[row,:] = 2 * sum_e val_e * Tcur[col_e,:] - Tprev[row,:]  (in-place into Tprev)
//   H[row,:]   += c[row,k] * Tnew[row,:]
// grid = (8, 2048): blockIdx.x = 256-col block -> linear%8 -> XCD-local L2 slice.
// ---------------------------------------------------------------------------
__global__ __launch_bounds__(64) void cheb_step(const float* __restrict__ Tcur,
                                                float* __restrict__ Tprev,
                                                float* __restrict__ H,
                                                const float* __restrict__ cc, int k,
                                                const int* __restrict__ cols,
                                                const float* __restrict__ vals,
                                                const int* __restrict__ lens) {
    int row = blockIdx.y;
    int col = blockIdx.x * 256 + threadIdx.x * 4;
    __shared__ float s_val[KMAX];
    __shared__ int   s_off[KMAX];
    int len = lens[row];
    for (int e = threadIdx.x; e < len; e += 64) {
        s_val[e] = 2.0f * vals[row * KMAX + e];
        s_off[e] = cols[row * KMAX + e] * N_NODES;
    }
    __syncthreads();
    float4 acc = make_float4(0.f, 0.f, 0.f, 0.f);
    for (int e = 0; e < len; ++e) {
        float v = s_val[e];
        float4 g = *(const float4*)(Tcur + (size_t)s_off[e] + col);
        acc.x += v * g.x; acc.y += v * g.y; acc.z += v * g.z; acc.w += v * g.w;
    }
    size_t off = (size_t)row * N_NODES + col;
    float4 tp = *(float4*)(Tprev + off);
    float4 tn;
    tn.x = acc.x - tp.x; tn.y = acc.y - tp.y; tn.z = acc.z - tp.z; tn.w = acc.w - tp.w;
    *(float4*)(Tprev + off) = tn;
    float ck = cc[row * (M_CHEB + 1) + k];
    float4 h = *(float4*)(H + off);
    h.x += ck * tn.x; h.y += ck * tn.y; h.z += ck * tn.z; h.w += ck * tn.w;
    *(float4*)(H + off) = h;
}

// ---------------------------------------------------------------------------
// Kernel 5: threshold H row, compact nonzeros to LDS, out[row,:] = H'row @ x.
// Also writes the t passthrough output tail.
// ---------------------------------------------------------------------------
__global__ __launch_bounds__(256) void final_kernel(const float* __restrict__ H,
                                                    const float* __restrict__ x,
                                                    const float* __restrict__ t,
                                                    float* __restrict__ out) {
    int row = blockIdx.x;
    __shared__ float s_v[N_NODES];
    __shared__ int   s_j[N_NODES];
    __shared__ int   cnt;
    if (threadIdx.x == 0) cnt = 0;
    __syncthreads();
    for (int base = 0; base < N_NODES; base += 1024) {
        int j = base + threadIdx.x * 4;
        float4 h = *(const float4*)(H + (size_t)row * N_NODES + j);
        if (h.x >= HK_THR) { int p = atomicAdd(&cnt, 1); s_v[p] = h.x; s_j[p] = j + 0; }
        if (h.y >= HK_THR) { int p = atomicAdd(&cnt, 1); s_v[p] = h.y; s_j[p] = j + 1; }
        if (h.z >= HK_THR) { int p = atomicAdd(&cnt, 1); s_v[p] = h.z; s_j[p] = j + 2; }
        if (h.w >= HK_THR) { int p = atomicAdd(&cnt, 1); s_v[p] = h.w; s_j[p] = j + 3; }
    }
    __syncthreads();
    int n = cnt;
    float2 acc = make_float2(0.f, 0.f);
    int f = threadIdx.x * 2;
    for (int e = 0; e < n; ++e) {
        float v = s_v[e];
        int   j = s_j[e];
        float2 xv = *(const float2*)(x + (size_t)j * N_FEAT + f);
        acc.x += v * xv.x;
        acc.y += v * xv.y;
    }
    *(float2*)(out + (size_t)row * N_FEAT + f) = acc;
    if (threadIdx.x == 0) out[(size_t)N_NODES * N_FEAT + row] = t[row];
}

// ---------------------------------------------------------------------------
extern "C" void kernel_launch(void* const* d_in, const int* in_sizes, int n_in,
                              void* d_out, int out_size, void* d_ws, size_t ws_size,
                              hipStream_t stream) {
    const float* x      = (const float*)d_in[0];   // [N,F]
    const float* P_n    = (const float*)d_in[1];   // [N,N]
    const float* t      = (const float*)d_in[2];   // [N]
    const float* eigmax = (const float*)d_in[3];   // [1]
    float* out = (float*)d_out;

    // workspace carve-up (all 256B-aligned)
    char* p = (char*)d_ws;
    auto carve = [&](size_t bytes) -> void* {
        void* r = (void*)p;
        p += (bytes + 255) & ~(size_t)255;
        return r;
    };
    float* cc   = (float*)carve((size_t)N_NODES * (M_CHEB + 1) * sizeof(float));
    float* vals = (float*)carve((size_t)N_NODES * KMAX * sizeof(float));
    int*   cols = (int*)  carve((size_t)N_NODES * KMAX * sizeof(int));
    int*   lens = (int*)  carve((size_t)N_NODES * sizeof(int));
    float* bufA = (float*)carve((size_t)N_NODES * N_NODES * sizeof(float));
    float* bufB = (float*)carve((size_t)N_NODES * N_NODES * sizeof(float));
    float* H    = (float*)carve((size_t)N_NODES * N_NODES * sizeof(float));

    coeff_kernel<<<dim3(N_NODES / 256), dim3(256), 0, stream>>>(t, eigmax, cc);
    csr_kernel<<<dim3(N_NODES), dim3(256), 0, stream>>>(P_n, eigmax, cols, vals, lens);
    init_kernel<<<dim3(8, N_NODES), dim3(64), 0, stream>>>(P_n, eigmax, cc, bufA, bufB, H);

    float* Tprev = bufA;  // T0 = I
    float* Tcur  = bufB;  // T1 = L_hat
    for (int k = 2; k <= M_CHEB; ++k) {
        cheb_step<<<dim3(8, N_NODES), dim3(64), 0, stream>>>(Tcur, Tprev, H, cc, k,
                                                             cols, vals, lens);
        float* tmp = Tprev;  // now holds T_k
        Tprev = Tcur;
        Tcur  = tmp;
    }

    final_kernel<<<dim3(N_NODES), dim3(256), 0, stream>>>(H, x, t, out);
}

// Round 3
// 239.198 us; speedup vs baseline: 1.8522x; 1.8522x over previous
//
#include <hip/hip_runtime.h>

#define NN   2048
#define NF   512
#define MCH  10
#define QQ   64
#define KMAX 128          // max nnz per row of L_hat (expected ~32, max ~60)
#define PI_F 3.14159265358979323846f

typedef __attribute__((ext_vector_type(4))) float f32x4;

// ---------------------------------------------------------------------------
// Kernel 1: per-node Chebyshev coefficients c[i,k] + t passthrough tail.
// ---------------------------------------------------------------------------
__global__ __launch_bounds__(256) void coeff_kernel(const float* __restrict__ t,
                                                    const float* __restrict__ eigmax,
                                                    float* __restrict__ cc,
                                                    float* __restrict__ out) {
    int i = blockIdx.x * 256 + threadIdx.x;
    if (i >= NN) return;
    float s  = expf(t[i]);
    float em = eigmax[0];
    float acc[MCH + 1];
#pragma unroll
    for (int k = 0; k <= MCH; ++k) acc[k] = 0.0f;
    for (int q = 0; q < QQ; ++q) {
        float th  = PI_F * ((float)q + 0.5f) / (float)QQ;
        float lam = em * 0.5f * (cosf(th) + 1.0f);
        float w   = expf(-s * lam);
#pragma unroll
        for (int k = 0; k <= MCH; ++k) acc[k] += w * cosf((float)k * th);
    }
#pragma unroll
    for (int k = 0; k <= MCH; ++k) {
        float v = acc[k] * (2.0f / (float)QQ);
        if (k == 0) v *= 0.5f;
        cc[i * (MCH + 1) + k] = v;
    }
    out[(size_t)NN * NF + i] = t[i];   // t passthrough (output tail)
}

// ---------------------------------------------------------------------------
// Kernel 2: fixed-width sparse rows of L_hat = (2/eig)*P - I.  (R1-verified)
// ---------------------------------------------------------------------------
__global__ __launch_bounds__(256) void csr_kernel(const float* __restrict__ P,
                                                  const float* __restrict__ eigmax,
                                                  int* __restrict__ cols,
                                                  float* __restrict__ vals,
                                                  int* __restrict__ lens) {
    int row = blockIdx.x;
    __shared__ int cnt;
    if (threadIdx.x == 0) cnt = 0;
    __syncthreads();
    float s2 = 2.0f / eigmax[0];
    for (int j = threadIdx.x; j < NN; j += 256) {
        float v = s2 * P[(size_t)row * NN + j] - (j == row ? 1.0f : 0.0f);
        if (v != 0.0f) {
            int p = atomicAdd(&cnt, 1);
            if (p < KMAX) {
                cols[row * KMAX + p] = j;
                vals[row * KMAX + p] = v;
            }
        }
    }
    __syncthreads();
    if (threadIdx.x == 0) lens[row] = min(cnt, KMAX);
}

// ---------------------------------------------------------------------------
// Kernel 3: init.  Y1 = L_hat @ x  (sparse gather), out = c0*x + c1*Y1.
// Grid (8, 256): bx = 64-col slice (linear%8 -> XCD-local), by = 8-row group.
// Block 128 threads: thread = (row_sub = t>>4, colq = t&15), f32x4 per thread.
// ---------------------------------------------------------------------------
__global__ __launch_bounds__(128) void cheb_init(
    const float* __restrict__ x, const float* __restrict__ cc,
    const int* __restrict__ cols, const float* __restrict__ vals,
    const int* __restrict__ lens,
    float* __restrict__ Y1, float* __restrict__ out) {
    __shared__ float s_val[8][KMAX];
    __shared__ int   s_off[8][KMAX];
    __shared__ int   s_len[8];
    const int r0  = blockIdx.y * 8;
    const int cb  = blockIdx.x * 64;
    const int tid = threadIdx.x;
    const int rs  = tid >> 4, cq = tid & 15;
    if (tid < 8) s_len[tid] = lens[r0 + tid];
    __syncthreads();
    for (int i = tid; i < 8 * KMAX; i += 128) {
        int r = i >> 7, e = i & (KMAX - 1);
        if (e < s_len[r]) {
            s_val[r][e] = vals[(r0 + r) * KMAX + e];
            s_off[r][e] = cols[(r0 + r) * KMAX + e] * NF + cb;
        }
    }
    __syncthreads();
    const int len  = s_len[rs];
    const int coff = cq * 4;
    const float* vr  = s_val[rs];
    const int*   orr = s_off[rs];
    f32x4 acc = {0.f, 0.f, 0.f, 0.f};
#pragma unroll 4
    for (int e = 0; e < len; ++e)
        acc += vr[e] * *(const f32x4*)(x + orr[e] + coff);
    const int row = r0 + rs;
    const size_t off = (size_t)row * NF + cb + coff;
    *(f32x4*)(Y1 + off) = acc;
    f32x4 xv = *(const f32x4*)(x + off);
    float c0 = cc[row * (MCH + 1) + 0];
    float c1 = cc[row * (MCH + 1) + 1];
    *(f32x4*)(out + off) = c0 * xv + c1 * acc;
}

// ---------------------------------------------------------------------------
// Kernel 4 (x9): Ynew = 2*L_hat@Ycur - Yprev;  out += c_k * Ynew.
// Yprev may alias Ynew (thread RMWs only its own elements -> race-free).
// ---------------------------------------------------------------------------
__global__ __launch_bounds__(128) void cheb_step(
    const float* __restrict__ Ycur,
    const float* Yprev, float* Ynew,
    const float* __restrict__ cc, int k,
    const int* __restrict__ cols, const float* __restrict__ vals,
    const int* __restrict__ lens, float* __restrict__ out) {
    __shared__ float s_val[8][KMAX];
    __shared__ int   s_off[8][KMAX];
    __shared__ int   s_len[8];
    const int r0  = blockIdx.y * 8;
    const int cb  = blockIdx.x * 64;
    const int tid = threadIdx.x;
    const int rs  = tid >> 4, cq = tid & 15;
    if (tid < 8) s_len[tid] = lens[r0 + tid];
    __syncthreads();
    for (int i = tid; i < 8 * KMAX; i += 128) {
        int r = i >> 7, e = i & (KMAX - 1);
        if (e < s_len[r]) {
            s_val[r][e] = 2.0f * vals[(r0 + r) * KMAX + e];
            s_off[r][e] = cols[(r0 + r) * KMAX + e] * NF + cb;
        }
    }
    __syncthreads();
    const int len  = s_len[rs];
    const int coff = cq * 4;
    const float* vr  = s_val[rs];
    const int*   orr = s_off[rs];
    f32x4 acc = {0.f, 0.f, 0.f, 0.f};
#pragma unroll 4
    for (int e = 0; e < len; ++e)
        acc += vr[e] * *(const f32x4*)(Ycur + orr[e] + coff);
    const int row = r0 + rs;
    const size_t off = (size_t)row * NF + cb + coff;
    f32x4 tp = *(const f32x4*)(Yprev + off);
    f32x4 tn = acc - tp;
    *(f32x4*)(Ynew + off) = tn;
    float ck = cc[row * (MCH + 1) + k];
    f32x4 o = *(f32x4*)(out + off);
    *(f32x4*)(out + off) = o + ck * tn;
}

// ---------------------------------------------------------------------------
extern "C" void kernel_launch(void* const* d_in, const int* in_sizes, int n_in,
                              void* d_out, int out_size, void* d_ws, size_t ws_size,
                              hipStream_t stream) {
    const float* x      = (const float*)d_in[0];   // [N,F]
    const float* P_n    = (const float*)d_in[1];   // [N,N]
    const float* t      = (const float*)d_in[2];   // [N]
    const float* eigmax = (const float*)d_in[3];   // [1]
    float* out = (float*)d_out;

    char* p = (char*)d_ws;
    auto carve = [&](size_t bytes) -> void* {
        void* r = (void*)p;
        p += (bytes + 255) & ~(size_t)255;
        return r;
    };
    float* cc   = (float*)carve((size_t)NN * (MCH + 1) * sizeof(float));
    float* vals = (float*)carve((size_t)NN * KMAX * sizeof(float));
    int*   cols = (int*)  carve((size_t)NN * KMAX * sizeof(int));
    int*   lens = (int*)  carve((size_t)NN * sizeof(int));
    float* bufA = (float*)carve((size_t)NN * NF * sizeof(float));
    float* bufB = (float*)carve((size_t)NN * NF * sizeof(float));

    coeff_kernel<<<dim3(NN / 256), dim3(256), 0, stream>>>(t, eigmax, cc, out);
    csr_kernel<<<dim3(NN), dim3(256), 0, stream>>>(P_n, eigmax, cols, vals, lens);

    dim3 grid(NF / 64, NN / 8);   // (8, 256)
    cheb_init<<<grid, dim3(128), 0, stream>>>(x, cc, cols, vals, lens, bufB, out);

    // Y rotation: Y0 = x, Y1 = bufB.  In-place: Ynew overwrites Yprev (k>=3).
    const float* cur  = bufB;
    const float* prev = x;
    float*       nxt  = bufA;
    for (int k = 2; k <= MCH; ++k) {
        cheb_step<<<grid, dim3(128), 0, stream>>>(cur, prev, nxt, cc, k,
                                                  cols, vals, lens, out);
        float* ocur = (float*)cur;
        prev = cur;
        cur  = nxt;
        nxt  = ocur;
    }
}

// Round 4
// 193.033 us; speedup vs baseline: 2.2951x; 1.2392x over previous
//
#include <hip/hip_runtime.h>

#define NN   2048
#define NF   512
#define MCH  10
#define QQ   64
#define KMAX 128          // max nnz per row of L_hat (expected ~32, max ~60)
#define KPAD (KMAX + 1)   // LDS row stride: 129 floats -> row r starts at bank r, kills 4-way conflicts
#define PI_F 3.14159265358979323846f

typedef __attribute__((ext_vector_type(4))) float f32x4;

// ---------------------------------------------------------------------------
// Kernel 1: per-node Chebyshev coefficients c[i,k] + t passthrough tail.
// cos(k*theta) via Chebyshev recurrence (64 precise cosf/thread, not 704);
// w = exp(-s*lam) via hardware __expf (1e-6 rel, negligible vs 0.086 budget).
// 32 blocks x 64 threads spreads over 32 CUs (was 8 blocks of 256).
// ---------------------------------------------------------------------------
__global__ __launch_bounds__(64) void coeff_kernel(const float* __restrict__ t,
                                                   const float* __restrict__ eigmax,
                                                   float* __restrict__ cc,
                                                   float* __restrict__ out) {
    int i = blockIdx.x * 64 + threadIdx.x;
    float s  = expf(t[i]);
    float em = eigmax[0];
    float acc[MCH + 1];
#pragma unroll
    for (int k = 0; k <= MCH; ++k) acc[k] = 0.0f;
    for (int q = 0; q < QQ; ++q) {
        float th = PI_F * ((float)q + 0.5f) / (float)QQ;
        float ct = cosf(th);                       // precise seed (recurrence amplifies ~k^2)
        float w  = __expf(-s * em * 0.5f * (ct + 1.0f));
        float ckm1 = 1.0f, ck = ct;
        acc[0] += w;
        acc[1] += w * ct;
#pragma unroll
        for (int k = 2; k <= MCH; ++k) {
            float cn = 2.0f * ct * ck - ckm1;
            acc[k] += w * cn;
            ckm1 = ck; ck = cn;
        }
    }
#pragma unroll
    for (int k = 0; k <= MCH; ++k) {
        float v = acc[k] * (2.0f / (float)QQ);
        if (k == 0) v *= 0.5f;
        cc[i * (MCH + 1) + k] = v;
    }
    out[(size_t)NN * NF + i] = t[i];   // t passthrough (output tail)
}

// ---------------------------------------------------------------------------
// Kernel 2: fixed-width sparse rows of L_hat = (2/eig)*P - I.  (R1-verified)
// ---------------------------------------------------------------------------
__global__ __launch_bounds__(256) void csr_kernel(const float* __restrict__ P,
                                                  const float* __restrict__ eigmax,
                                                  int* __restrict__ cols,
                                                  float* __restrict__ vals,
                                                  int* __restrict__ lens) {
    int row = blockIdx.x;
    __shared__ int cnt;
    if (threadIdx.x == 0) cnt = 0;
    __syncthreads();
    float s2 = 2.0f / eigmax[0];
    for (int j = threadIdx.x; j < NN; j += 256) {
        float v = s2 * P[(size_t)row * NN + j] - (j == row ? 1.0f : 0.0f);
        if (v != 0.0f) {
            int p = atomicAdd(&cnt, 1);
            if (p < KMAX) {
                cols[row * KMAX + p] = j;
                vals[row * KMAX + p] = v;
            }
        }
    }
    __syncthreads();
    if (threadIdx.x == 0) lens[row] = min(cnt, KMAX);
}

// ---------------------------------------------------------------------------
// Kernel 3: init.  Y1 = L_hat @ x  (sparse gather), out = c0*x + c1*Y1.
// Grid (8, 256): bx = 64-col slice (linear%8 -> XCD-local), by = 8-row group.
// ---------------------------------------------------------------------------
__global__ __launch_bounds__(128) void cheb_init(
    const float* __restrict__ x, const float* __restrict__ cc,
    const int* __restrict__ cols, const float* __restrict__ vals,
    const int* __restrict__ lens,
    float* __restrict__ Y1, float* __restrict__ out) {
    __shared__ float s_val[8][KPAD];
    __shared__ int   s_off[8][KPAD];
    __shared__ int   s_len[8];
    const int r0  = blockIdx.y * 8;
    const int cb  = blockIdx.x * 64;
    const int tid = threadIdx.x;
    const int rs  = tid >> 4, cq = tid & 15;
    if (tid < 8) s_len[tid] = lens[r0 + tid];
    __syncthreads();
    for (int i = tid; i < 8 * KMAX; i += 128) {
        int r = i >> 7, e = i & (KMAX - 1);
        if (e < s_len[r]) {
            s_val[r][e] = vals[(r0 + r) * KMAX + e];
            s_off[r][e] = cols[(r0 + r) * KMAX + e] * NF + cb;
        }
    }
    __syncthreads();
    const int len  = s_len[rs];
    const int coff = cq * 4;
    const float* vr  = s_val[rs];
    const int*   orr = s_off[rs];
    f32x4 acc = {0.f, 0.f, 0.f, 0.f};
#pragma unroll 8
    for (int e = 0; e < len; ++e)
        acc += vr[e] * *(const f32x4*)(x + orr[e] + coff);
    const int row = r0 + rs;
    const size_t off = (size_t)row * NF + cb + coff;
    *(f32x4*)(Y1 + off) = acc;
    f32x4 xv = *(const f32x4*)(x + off);
    float c0 = cc[row * (MCH + 1) + 0];
    float c1 = cc[row * (MCH + 1) + 1];
    *(f32x4*)(out + off) = c0 * xv + c1 * acc;
}

// ---------------------------------------------------------------------------
// Kernel 4 (x9): Ynew = 2*L_hat@Ycur - Yprev;  out += c_k * Ynew.
// Yprev may alias Ynew (thread RMWs only its own elements -> race-free).
// ---------------------------------------------------------------------------
__global__ __launch_bounds__(128) void cheb_step(
    const float* __restrict__ Ycur,
    const float* Yprev, float* Ynew,
    const float* __restrict__ cc, int k,
    const int* __restrict__ cols, const float* __restrict__ vals,
    const int* __restrict__ lens, float* __restrict__ out) {
    __shared__ float s_val[8][KPAD];
    __shared__ int   s_off[8][KPAD];
    __shared__ int   s_len[8];
    const int r0  = blockIdx.y * 8;
    const int cb  = blockIdx.x * 64;
    const int tid = threadIdx.x;
    const int rs  = tid >> 4, cq = tid & 15;
    if (tid < 8) s_len[tid] = lens[r0 + tid];
    __syncthreads();
    for (int i = tid; i < 8 * KMAX; i += 128) {
        int r = i >> 7, e = i & (KMAX - 1);
        if (e < s_len[r]) {
            s_val[r][e] = 2.0f * vals[(r0 + r) * KMAX + e];
            s_off[r][e] = cols[(r0 + r) * KMAX + e] * NF + cb;
        }
    }
    __syncthreads();
    const int len  = s_len[rs];
    const int coff = cq * 4;
    const float* vr  = s_val[rs];
    const int*   orr = s_off[rs];
    f32x4 acc = {0.f, 0.f, 0.f, 0.f};
#pragma unroll 8
    for (int e = 0; e < len; ++e)
        acc += vr[e] * *(const f32x4*)(Ycur + orr[e] + coff);
    const int row = r0 + rs;
    const size_t off = (size_t)row * NF + cb + coff;
    f32x4 tp = *(const f32x4*)(Yprev + off);
    f32x4 tn = acc - tp;
    *(f32x4*)(Ynew + off) = tn;
    float ck = cc[row * (MCH + 1) + k];
    f32x4 o = *(f32x4*)(out + off);
    *(f32x4*)(out + off) = o + ck * tn;
}

// ---------------------------------------------------------------------------
extern "C" void kernel_launch(void* const* d_in, const int* in_sizes, int n_in,
                              void* d_out, int out_size, void* d_ws, size_t ws_size,
                              hipStream_t stream) {
    const float* x      = (const float*)d_in[0];   // [N,F]
    const float* P_n    = (const float*)d_in[1];   // [N,N]
    const float* t      = (const float*)d_in[2];   // [N]
    const float* eigmax = (const float*)d_in[3];   // [1]
    float* out = (float*)d_out;

    char* p = (char*)d_ws;
    auto carve = [&](size_t bytes) -> void* {
        void* r = (void*)p;
        p += (bytes + 255) & ~(size_t)255;
        return r;
    };
    float* cc   = (float*)carve((size_t)NN * (MCH + 1) * sizeof(float));
    float* vals = (float*)carve((size_t)NN * KMAX * sizeof(float));
    int*   cols = (int*)  carve((size_t)NN * KMAX * sizeof(int));
    int*   lens = (int*)  carve((size_t)NN * sizeof(int));
    float* bufA = (float*)carve((size_t)NN * NF * sizeof(float));
    float* bufB = (float*)carve((size_t)NN * NF * sizeof(float));

    coeff_kernel<<<dim3(NN / 64), dim3(64), 0, stream>>>(t, eigmax, cc, out);
    csr_kernel<<<dim3(NN), dim3(256), 0, stream>>>(P_n, eigmax, cols, vals, lens);

    dim3 grid(NF / 64, NN / 8);   // (8, 256)
    cheb_init<<<grid, dim3(128), 0, stream>>>(x, cc, cols, vals, lens, bufB, out);

    // Y rotation: Y0 = x, Y1 = bufB.  In-place: Ynew overwrites Yprev (k>=3).
    const float* cur  = bufB;
    const float* prev = x;
    float*       nxt  = bufA;
    for (int k = 2; k <= MCH; ++k) {
        cheb_step<<<grid, dim3(128), 0, stream>>>(cur, prev, nxt, cc, k,
                                                  cols, vals, lens, out);
        float* ocur = (float*)cur;
        prev = cur;
        cur  = nxt;
        nxt  = ocur;
    }
}

// Round 5
// 163.185 us; speedup vs baseline: 2.7149x; 1.1829x over previous
//
#include <hip/hip_runtime.h>
#include <hip/hip_fp16.h>

#define NN   2048
#define NF   512
#define MCH  10
#define QQ   64
#define KMAX 128          // max nnz per row of L_hat (expected ~32, max ~60)
#define PI_F 3.14159265358979323846f

// ---------------------------------------------------------------------------
// Kernel 1: per-node Chebyshev coefficients, TRANSPOSED cc_cm[k][i] for
// coalesced per-step reads in the fused kernel.  + t passthrough tail.
// cos(k*th) via recurrence; w via hardware __expf.
// ---------------------------------------------------------------------------
__global__ __launch_bounds__(64) void coeff_kernel(const float* __restrict__ t,
                                                   const float* __restrict__ eigmax,
                                                   float* __restrict__ cc_cm,
                                                   float* __restrict__ out) {
    int i = blockIdx.x * 64 + threadIdx.x;
    float s  = expf(t[i]);
    float em = eigmax[0];
    float acc[MCH + 1];
#pragma unroll
    for (int k = 0; k <= MCH; ++k) acc[k] = 0.0f;
    for (int q = 0; q < QQ; ++q) {
        float th = PI_F * ((float)q + 0.5f) / (float)QQ;
        float ct = cosf(th);                       // precise seed
        float w  = __expf(-s * em * 0.5f * (ct + 1.0f));
        float ckm1 = 1.0f, ck = ct;
        acc[0] += w;
        acc[1] += w * ct;
#pragma unroll
        for (int k = 2; k <= MCH; ++k) {
            float cn = 2.0f * ct * ck - ckm1;
            acc[k] += w * cn;
            ckm1 = ck; ck = cn;
        }
    }
#pragma unroll
    for (int k = 0; k <= MCH; ++k) {
        float v = acc[k] * (2.0f / (float)QQ);
        if (k == 0) v *= 0.5f;
        cc_cm[k * NN + i] = v;
    }
    out[(size_t)NN * NF + i] = t[i];   // t passthrough (output tail)
}

// ---------------------------------------------------------------------------
// Kernel 2: e-major packed CSR of L_hat = (2/eig)*P - I.
// packed[e*NN + row] = (col << 16) | f16(val).  Immutable across steps ->
// stays L2-resident in the fused kernel (no coherence traffic).
// ---------------------------------------------------------------------------
__global__ __launch_bounds__(256) void csr_kernel(const float* __restrict__ P,
                                                  const float* __restrict__ eigmax,
                                                  unsigned* __restrict__ packed,
                                                  int* __restrict__ lens) {
    int row = blockIdx.x;
    __shared__ int cnt;
    if (threadIdx.x == 0) cnt = 0;
    __syncthreads();
    float s2 = 2.0f / eigmax[0];
    for (int j = threadIdx.x; j < NN; j += 256) {
        float v = s2 * P[(size_t)row * NN + j] - (j == row ? 1.0f : 0.0f);
        if (v != 0.0f) {
            int p = atomicAdd(&cnt, 1);
            if (p < KMAX) {
                unsigned short hb = __half_as_ushort(__float2half_rn(v));
                packed[(size_t)p * NN + row] = ((unsigned)j << 16) | (unsigned)hb;
            }
        }
    }
    __syncthreads();
    if (threadIdx.x == 0) lens[row] = min(cnt, KMAX);
}

// ---------------------------------------------------------------------------
// Kernel 3: FUSED recurrence.  One block per 2-column slice (256 blocks, one
// per CU).  Both T buffers for the slice live in LDS (2 x 16 KB); the whole
// 9-step recurrence needs only __syncthreads().  Gathers are ds_read_b64;
// only repeated global reads are the immutable packed CSR (L2-hot).
// Thread owns rows {tid, tid+1024} x 2 cols; H accumulator in registers.
// ---------------------------------------------------------------------------
__global__ __launch_bounds__(1024) void cheb_fused(
    const float* __restrict__ x, const float* __restrict__ cc_cm,
    const unsigned* __restrict__ packed, const int* __restrict__ lens,
    float* __restrict__ out) {
    __shared__ float S[2][NN * 2];

    const int tid = threadIdx.x;
    const int c0  = blockIdx.x * 2;
    const int r0  = tid;
    const int r1  = tid + 1024;

    // stage x slice into S[0]  (T0 = x for the Y-recurrence)
    float2 x0 = *(const float2*)(x + (size_t)r0 * NF + c0);
    float2 x1 = *(const float2*)(x + (size_t)r1 * NF + c0);
    *(float2*)&S[0][2 * r0] = x0;
    *(float2*)&S[0][2 * r1] = x1;
    const int len0 = lens[r0];
    const int len1 = lens[r1];
    __syncthreads();

    // gather lambda: sum_e val[r,e] * S[buf][col[r,e]]
    auto gather = [&](int buf, int r, int len) -> float2 {
        float gx = 0.f, gy = 0.f;
#pragma unroll 4
        for (int e = 0; e < len; ++e) {
            unsigned pk = packed[(size_t)e * NN + r];       // coalesced (lanes = rows)
            int   c = (int)(pk >> 16);
            float v = __half2float(__ushort_as_half((unsigned short)(pk & 0xffffu)));
            float2 g = *(const float2*)&S[buf][2 * c];      // ds_read_b64, random row
            gx += v * g.x;
            gy += v * g.y;
        }
        return make_float2(gx, gy);
    };

    // T1 = L_hat @ x  -> S[1];  H = c0*T0 + c1*T1
    float2 a0 = gather(0, r0, len0);
    float2 a1 = gather(0, r1, len1);
    *(float2*)&S[1][2 * r0] = a0;
    *(float2*)&S[1][2 * r1] = a1;
    float cA0 = cc_cm[r0], cB0 = cc_cm[NN + r0];
    float cA1 = cc_cm[r1], cB1 = cc_cm[NN + r1];
    float2 H0 = make_float2(cA0 * x0.x + cB0 * a0.x, cA0 * x0.y + cB0 * a0.y);
    float2 H1 = make_float2(cA1 * x1.x + cB1 * a1.x, cA1 * x1.y + cB1 * a1.y);

    int cur = 1;
    for (int k = 2; k <= MCH; ++k) {
        __syncthreads();   // step k-1 writes into S[cur] visible; S[1-cur] reads done
        float2 g0 = gather(cur, r0, len0);
        float2 g1 = gather(cur, r1, len1);
        int oth = 1 - cur;
        float2 p0 = *(const float2*)&S[oth][2 * r0];
        float2 p1 = *(const float2*)&S[oth][2 * r1];
        float2 t0 = make_float2(2.f * g0.x - p0.x, 2.f * g0.y - p0.y);
        float2 t1 = make_float2(2.f * g1.x - p1.x, 2.f * g1.y - p1.y);
        *(float2*)&S[oth][2 * r0] = t0;   // own slot only: race-free
        *(float2*)&S[oth][2 * r1] = t1;
        float ck0 = cc_cm[k * NN + r0];
        float ck1 = cc_cm[k * NN + r1];
        H0.x += ck0 * t0.x; H0.y += ck0 * t0.y;
        H1.x += ck1 * t1.x; H1.y += ck1 * t1.y;
        cur = oth;
    }

    *(float2*)(out + (size_t)r0 * NF + c0) = H0;
    *(float2*)(out + (size_t)r1 * NF + c0) = H1;
}

// ---------------------------------------------------------------------------
extern "C" void kernel_launch(void* const* d_in, const int* in_sizes, int n_in,
                              void* d_out, int out_size, void* d_ws, size_t ws_size,
                              hipStream_t stream) {
    const float* x      = (const float*)d_in[0];   // [N,F]
    const float* P_n    = (const float*)d_in[1];   // [N,N]
    const float* t      = (const float*)d_in[2];   // [N]
    const float* eigmax = (const float*)d_in[3];   // [1]
    float* out = (float*)d_out;

    char* p = (char*)d_ws;
    auto carve = [&](size_t bytes) -> void* {
        void* r = (void*)p;
        p += (bytes + 255) & ~(size_t)255;
        return r;
    };
    float*    cc_cm  = (float*)   carve((size_t)(MCH + 1) * NN * sizeof(float));
    unsigned* packed = (unsigned*)carve((size_t)KMAX * NN * sizeof(unsigned));
    int*      lens   = (int*)     carve((size_t)NN * sizeof(int));

    coeff_kernel<<<dim3(NN / 64), dim3(64), 0, stream>>>(t, eigmax, cc_cm, out);
    csr_kernel<<<dim3(NN), dim3(256), 0, stream>>>(P_n, eigmax, packed, lens);
    cheb_fused<<<dim3(NF / 2), dim3(1024), 0, stream>>>(x, cc_cm, packed, lens, out);
}

// Round 6
// 129.193 us; speedup vs baseline: 3.4293x; 1.2631x over previous
//
#include <hip/hip_runtime.h>
#include <hip/hip_fp16.h>

#define NN   2048
#define NF   512
#define MCH  10
#define QQ   64
#define KMAX 128          // max nnz per row of L_hat (expected ~32, max ~60)
#define TOL  2e-3f        // truncation budget (absmax threshold is 0.086)
#define PI_F 3.14159265358979323846f

// ---------------------------------------------------------------------------
// Kernel 1: e-major packed CSR of L_hat = (2/eig)*P - I:
//   packed[e*NN + row] = (col << 16) | f16(val)
// Plus: per-row-block max|x| partials for the truncation bound (block b scans
// x[b*512 .. b*512+512), so 2048 blocks cover all of x). Race-free: each
// bmax slot is written exactly once.
// ---------------------------------------------------------------------------
__global__ __launch_bounds__(256) void csr_kernel(const float* __restrict__ P,
                                                  const float* __restrict__ eigmax,
                                                  const float* __restrict__ x,
                                                  unsigned* __restrict__ packed,
                                                  int* __restrict__ lens,
                                                  float* __restrict__ bmax) {
    int row = blockIdx.x;
    __shared__ int cnt;
    if (threadIdx.x == 0) cnt = 0;
    __syncthreads();
    float s2 = 2.0f / eigmax[0];
    for (int j = threadIdx.x; j < NN; j += 256) {
        float v = s2 * P[(size_t)row * NN + j] - (j == row ? 1.0f : 0.0f);
        if (v != 0.0f) {
            int p = atomicAdd(&cnt, 1);
            if (p < KMAX) {
                unsigned short hb = __half_as_ushort(__float2half_rn(v));
                packed[(size_t)p * NN + row] = ((unsigned)j << 16) | (unsigned)hb;
            }
        }
    }
    // max|x| over this block's 512-float slice
    const float* xs = x + (size_t)row * 512;
    float m = fmaxf(fabsf(xs[threadIdx.x]), fabsf(xs[threadIdx.x + 256]));
#pragma unroll
    for (int o = 32; o > 0; o >>= 1) m = fmaxf(m, __shfl_down(m, o));
    __shared__ float wm[4];
    if ((threadIdx.x & 63) == 0) wm[threadIdx.x >> 6] = m;
    __syncthreads();
    if (threadIdx.x == 0) {
        bmax[row] = fmaxf(fmaxf(wm[0], wm[1]), fmaxf(wm[2], wm[3]));
        lens[row] = min(cnt, KMAX);
    }
}

// ---------------------------------------------------------------------------
// Kernel 2: coefficients (transposed cc_cm[k][i]), t passthrough, and the
// adaptive truncation order K.  Block = 1 wave of 64.  Each thread builds the
// suffix sum of |c[i,k]| and finds the smallest K with
// tail(K) * sqrt(NN) * max|x| <= TOL  (since |Y_k| <= ||x[:,f]||_2 <= that).
// Per-block K maxes go to kslots[] (plain stores, race-free).
// ---------------------------------------------------------------------------
__global__ __launch_bounds__(64) void coeff_kernel(const float* __restrict__ t,
                                                   const float* __restrict__ eigmax,
                                                   const float* __restrict__ bmax,
                                                   float* __restrict__ cc_cm,
                                                   int* __restrict__ kslots,
                                                   float* __restrict__ out) {
    int i = blockIdx.x * 64 + threadIdx.x;
    float s  = expf(t[i]);
    float em = eigmax[0];
    float acc[MCH + 1];
#pragma unroll
    for (int k = 0; k <= MCH; ++k) acc[k] = 0.0f;
    for (int q = 0; q < QQ; ++q) {
        float th = PI_F * ((float)q + 0.5f) / (float)QQ;
        float ct = cosf(th);                       // precise seed
        float w  = __expf(-s * em * 0.5f * (ct + 1.0f));
        float ckm1 = 1.0f, ck = ct;
        acc[0] += w;
        acc[1] += w * ct;
#pragma unroll
        for (int k = 2; k <= MCH; ++k) {
            float cn = 2.0f * ct * ck - ckm1;
            acc[k] += w * cn;
            ckm1 = ck; ck = cn;
        }
    }
    float c[MCH + 1];
#pragma unroll
    for (int k = 0; k <= MCH; ++k) {
        float v = acc[k] * (2.0f / (float)QQ);
        if (k == 0) v *= 0.5f;
        c[k] = v;
        cc_cm[k * NN + i] = v;
    }
    out[(size_t)NN * NF + i] = t[i];   // t passthrough (output tail)

    // reduce max|x| over all 2048 partials
    float B = 0.f;
    for (int j = threadIdx.x; j < NN; j += 64) B = fmaxf(B, bmax[j]);
#pragma unroll
    for (int o = 32; o > 0; o >>= 1) B = fmaxf(B, __shfl_down(B, o));
    B = __shfl(B, 0);
    float bound = 45.2548f * B;        // sqrt(2048) * max|x|  >= ||x[:,f]||_2

    float tail = 0.f;
    int Ki = 1;
    for (int k = MCH; k >= 2; --k) {   // tail(K) = sum_{k>K} |c_k|
        tail += fabsf(c[k]);
        if (tail * bound > TOL) { Ki = k; break; }
    }
#pragma unroll
    for (int o = 32; o > 0; o >>= 1) Ki = max(Ki, __shfl_down(Ki, o));
    if (threadIdx.x == 0) kslots[blockIdx.x] = Ki;
}

// ---------------------------------------------------------------------------
// Kernel 3: fused recurrence, one block per 2-column slice (256 blocks).
// Y slice stored in LDS as packed half2 (1 word per row): gathers are
// ds_read_b32 (half the bank requests of R5's b64).  Loop runs k=2..K with
// K read from kslots (uniform).  H accumulator in fp32 registers.
// ---------------------------------------------------------------------------
__global__ __launch_bounds__(1024) void cheb_fused(
    const float* __restrict__ x, const float* __restrict__ cc_cm,
    const unsigned* __restrict__ packed, const int* __restrict__ lens,
    const int* __restrict__ kslots, float* __restrict__ out) {
    __shared__ unsigned S[2][NN];
    __shared__ int sK[32];

    const int tid = threadIdx.x;
    const int c0  = blockIdx.x * 2;
    const int r0  = tid;
    const int r1  = tid + 1024;

    if (tid < 32) sK[tid] = kslots[tid];

    float2 x0 = *(const float2*)(x + (size_t)r0 * NF + c0);
    float2 x1 = *(const float2*)(x + (size_t)r1 * NF + c0);
    {
        __half2 h0 = __floats2half2_rn(x0.x, x0.y);
        __half2 h1 = __floats2half2_rn(x1.x, x1.y);
        S[0][r0] = *(unsigned*)&h0;
        S[0][r1] = *(unsigned*)&h1;
    }
    const int len0 = lens[r0];
    const int len1 = lens[r1];
    __syncthreads();

    int K = 1;
#pragma unroll
    for (int b = 0; b < 32; ++b) K = max(K, sK[b]);

    auto gather = [&](int buf, int r, int len) -> float2 {
        float gx = 0.f, gy = 0.f;
#pragma unroll 8
        for (int e = 0; e < len; ++e) {
            unsigned pk = packed[(size_t)e * NN + r];           // coalesced
            float v = __half2float(__ushort_as_half((unsigned short)(pk & 0xffffu)));
            unsigned su = S[buf][pk >> 16];                     // ds_read_b32
            float2 g = __half22float2(*(__half2*)&su);
            gx += v * g.x;
            gy += v * g.y;
        }
        return make_float2(gx, gy);
    };

    // Y1 = L_hat @ x ;  H = c0*x + c1*Y1
    float2 a0 = gather(0, r0, len0);
    float2 a1 = gather(0, r1, len1);
    {
        __half2 h0 = __floats2half2_rn(a0.x, a0.y);
        __half2 h1 = __floats2half2_rn(a1.x, a1.y);
        S[1][r0] = *(unsigned*)&h0;
        S[1][r1] = *(unsigned*)&h1;
    }
    float cA0 = cc_cm[r0], cB0 = cc_cm[NN + r0];
    float cA1 = cc_cm[r1], cB1 = cc_cm[NN + r1];
    float2 H0 = make_float2(cA0 * x0.x + cB0 * a0.x, cA0 * x0.y + cB0 * a0.y);
    float2 H1 = make_float2(cA1 * x1.x + cB1 * a1.x, cA1 * x1.y + cB1 * a1.y);

    int cur = 1;
    for (int k = 2; k <= K; ++k) {
        __syncthreads();
        float2 g0 = gather(cur, r0, len0);
        float2 g1 = gather(cur, r1, len1);
        int oth = cur ^ 1;
        unsigned pu0 = S[oth][r0], pu1 = S[oth][r1];
        float2 p0 = __half22float2(*(__half2*)&pu0);
        float2 p1 = __half22float2(*(__half2*)&pu1);
        float2 t0 = make_float2(2.f * g0.x - p0.x, 2.f * g0.y - p0.y);
        float2 t1 = make_float2(2.f * g1.x - p1.x, 2.f * g1.y - p1.y);
        __syncthreads();   // everyone done reading S[oth] before overwrite
        {
            __half2 h0 = __floats2half2_rn(t0.x, t0.y);
            __half2 h1 = __floats2half2_rn(t1.x, t1.y);
            S[oth][r0] = *(unsigned*)&h0;
            S[oth][r1] = *(unsigned*)&h1;
        }
        float ck0 = cc_cm[k * NN + r0];
        float ck1 = cc_cm[k * NN + r1];
        H0.x += ck0 * t0.x; H0.y += ck0 * t0.y;
        H1.x += ck1 * t1.x; H1.y += ck1 * t1.y;
        cur = oth;
    }

    *(float2*)(out + (size_t)r0 * NF + c0) = H0;
    *(float2*)(out + (size_t)r1 * NF + c0) = H1;
}

// ---------------------------------------------------------------------------
extern "C" void kernel_launch(void* const* d_in, const int* in_sizes, int n_in,
                              void* d_out, int out_size, void* d_ws, size_t ws_size,
                              hipStream_t stream) {
    const float* x      = (const float*)d_in[0];   // [N,F]
    const float* P_n    = (const float*)d_in[1];   // [N,N]
    const float* t      = (const float*)d_in[2];   // [N]
    const float* eigmax = (const float*)d_in[3];   // [1]
    float* out = (float*)d_out;

    char* p = (char*)d_ws;
    auto carve = [&](size_t bytes) -> void* {
        void* r = (void*)p;
        p += (bytes + 255) & ~(size_t)255;
        return r;
    };
    float*    cc_cm  = (float*)   carve((size_t)(MCH + 1) * NN * sizeof(float));
    unsigned* packed = (unsigned*)carve((size_t)KMAX * NN * sizeof(unsigned));
    int*      lens   = (int*)     carve((size_t)NN * sizeof(int));
    float*    bmax   = (float*)   carve((size_t)NN * sizeof(float));
    int*      kslots = (int*)     carve((size_t)32 * sizeof(int));

    csr_kernel<<<dim3(NN), dim3(256), 0, stream>>>(P_n, eigmax, x, packed, lens, bmax);
    coeff_kernel<<<dim3(NN / 64), dim3(64), 0, stream>>>(t, eigmax, bmax, cc_cm, kslots, out);
    cheb_fused<<<dim3(NF / 2), dim3(1024), 0, stream>>>(x, cc_cm, packed, lens, kslots, out);
}

// Round 8
// 118.944 us; speedup vs baseline: 3.7247x; 1.0862x over previous
//
#include <hip/hip_runtime.h>
#include <hip/hip_fp16.h>

#define NN   2048
#define NF   512
#define MCH  10
#define QQ   64
#define KMAX 128          // max nnz per row of L_hat (expected ~32, max ~60)
#define TOL  2e-3f        // truncation budget (absmax threshold is 0.086)
#define PI_F 3.14159265358979323846f

__device__ inline float2 h2f2(unsigned u) { return __half22float2(*(__half2*)&u); }
__device__ inline unsigned f2h2(float a, float b) {
    __half2 h = __floats2half2_rn(a, b);
    return *(unsigned*)&h;
}

// ---------------------------------------------------------------------------
// Kernel A: transpose-cast x[r][f] (f32) -> xT[f][r] (f16) + per-block max|x|.
// grid (NN/64, NF/64) = (32, 8), block 256.  Both directions coalesced.
// ---------------------------------------------------------------------------
__global__ __launch_bounds__(256) void xpose_in(const float* __restrict__ x,
                                                unsigned short* __restrict__ xT,
                                                float* __restrict__ pmax) {
    __shared__ float tile[64][65];
    __shared__ float wm[4];
    int r0 = blockIdx.x * 64;
    int f0 = blockIdx.y * 64;
    int tx = threadIdx.x & 63, ty = threadIdx.x >> 6;
    float m = 0.f;
#pragma unroll
    for (int i = 0; i < 16; ++i) {
        int rr = ty * 16 + i;
        float v = x[(size_t)(r0 + rr) * NF + f0 + tx];
        tile[rr][tx] = v;
        m = fmaxf(m, fabsf(v));
    }
    __syncthreads();
#pragma unroll
    for (int i = 0; i < 16; ++i) {
        int ff = ty * 16 + i;
        __half h = __float2half_rn(tile[tx][ff]);
        xT[(size_t)(f0 + ff) * NN + r0 + tx] = __half_as_ushort(h);
    }
#pragma unroll
    for (int o = 32; o > 0; o >>= 1) m = fmaxf(m, __shfl_down(m, o));
    if ((threadIdx.x & 63) == 0) wm[threadIdx.x >> 6] = m;
    __syncthreads();
    if (threadIdx.x == 0)
        pmax[blockIdx.y * 32 + blockIdx.x] = fmaxf(fmaxf(wm[0], wm[1]), fmaxf(wm[2], wm[3]));
}

// ---------------------------------------------------------------------------
// Kernel B: e-major packed CSR of L_hat = (2/eig)*P - I.
//   packed[e*NN + row] = (col*4) << 16 | f16(val)   (byte offset pre-shifted)
// ---------------------------------------------------------------------------
__global__ __launch_bounds__(256) void csr_kernel(const float* __restrict__ P,
                                                  const float* __restrict__ eigmax,
                                                  unsigned* __restrict__ packed,
                                                  int* __restrict__ lens) {
    int row = blockIdx.x;
    __shared__ int cnt;
    if (threadIdx.x == 0) cnt = 0;
    __syncthreads();
    float s2 = 2.0f / eigmax[0];
    for (int j = threadIdx.x; j < NN; j += 256) {
        float v = s2 * P[(size_t)row * NN + j] - (j == row ? 1.0f : 0.0f);
        if (v != 0.0f) {
            int p = atomicAdd(&cnt, 1);
            if (p < KMAX) {
                unsigned short hb = __half_as_ushort(__float2half_rn(v));
                packed[(size_t)p * NN + row] = ((unsigned)j << 18) | (unsigned)hb;
            }
        }
    }
    __syncthreads();
    if (threadIdx.x == 0) lens[row] = min(cnt, KMAX);
}

// ---------------------------------------------------------------------------
// Kernel C: coefficients (transposed cc_cm[k][i]), t passthrough, adaptive K.
// ---------------------------------------------------------------------------
__global__ __launch_bounds__(64) void coeff_kernel(const float* __restrict__ t,
                                                   const float* __restrict__ eigmax,
                                                   const float* __restrict__ pmax,
                                                   float* __restrict__ cc_cm,
                                                   int* __restrict__ kslots,
                                                   float* __restrict__ out) {
    int i = blockIdx.x * 64 + threadIdx.x;
    float s  = expf(t[i]);
    float em = eigmax[0];
    float acc[MCH + 1];
#pragma unroll
    for (int k = 0; k <= MCH; ++k) acc[k] = 0.0f;
    for (int q = 0; q < QQ; ++q) {
        float th = PI_F * ((float)q + 0.5f) / (float)QQ;
        float ct = cosf(th);                       // precise seed
        float w  = __expf(-s * em * 0.5f * (ct + 1.0f));
        float ckm1 = 1.0f, ck = ct;
        acc[0] += w;
        acc[1] += w * ct;
#pragma unroll
        for (int k = 2; k <= MCH; ++k) {
            float cn = 2.0f * ct * ck - ckm1;
            acc[k] += w * cn;
            ckm1 = ck; ck = cn;
        }
    }
    float c[MCH + 1];
#pragma unroll
    for (int k = 0; k <= MCH; ++k) {
        float v = acc[k] * (2.0f / (float)QQ);
        if (k == 0) v *= 0.5f;
        c[k] = v;
        cc_cm[k * NN + i] = v;
    }
    out[(size_t)NN * NF + i] = t[i];   // t passthrough (output tail)

    float B = 0.f;
    for (int j = threadIdx.x; j < 256; j += 64) B = fmaxf(B, pmax[j]);
#pragma unroll
    for (int o = 32; o > 0; o >>= 1) B = fmaxf(B, __shfl_down(B, o));
    B = __shfl(B, 0);
    float bound = 45.2548f * B;        // sqrt(2048) * max|x| >= ||x[:,f]||_2 >= |Y_k|

    float tail = 0.f;
    int Ki = 1;
    for (int k = MCH; k >= 2; --k) {   // tail(K) = sum_{k>K} |c_k|
        tail += fabsf(c[k]);
        if (tail * bound > TOL) { Ki = k; break; }
    }
#pragma unroll
    for (int o = 32; o > 0; o >>= 1) Ki = max(Ki, __shfl_down(Ki, o));
    if (threadIdx.x == 0) kslots[blockIdx.x] = Ki;
}

// ---------------------------------------------------------------------------
// Kernel D: fused recurrence.  256 blocks x 1024; block = 2-column slice.
// Y slice as half2 in LDS; gather inner loop ~5 VALU ops/entry via
// pre-shifted byte offsets, v_perm val-dup, and v_pk_fma_f16.
// Coalesced I/O via xT / outT (column-major).
// ---------------------------------------------------------------------------
__global__ __launch_bounds__(1024) void cheb_fused(
    const unsigned short* __restrict__ xT, const float* __restrict__ cc_cm,
    const unsigned* __restrict__ packed, const int* __restrict__ lens,
    const int* __restrict__ kslots, float* __restrict__ outT) {
    __shared__ unsigned S[2][NN];
    __shared__ int sK[32];

    const int tid = threadIdx.x;
    const int c0  = blockIdx.x * 2;
    const int r0  = tid;
    const int r1  = tid + 1024;

    if (tid < 32) sK[tid] = kslots[tid];

    unsigned X0 = (unsigned)xT[(size_t)c0 * NN + r0] |
                  ((unsigned)xT[(size_t)(c0 + 1) * NN + r0] << 16);
    unsigned X1 = (unsigned)xT[(size_t)c0 * NN + r1] |
                  ((unsigned)xT[(size_t)(c0 + 1) * NN + r1] << 16);
    S[0][r0] = X0;
    S[0][r1] = X1;
    const int len0 = lens[r0];
    const int len1 = lens[r1];
    __syncthreads();

    int K = 1;
#pragma unroll
    for (int b = 0; b < 32; ++b) K = max(K, sK[b]);

    auto gather = [&](int buf, int r, int len) -> unsigned {
        const char* Sb = (const char*)S[buf];
        unsigned accu = 0u;
        __half2 acc = *(__half2*)&accu;
#pragma unroll 8
        for (int e = 0; e < len; ++e) {
            unsigned pk = packed[(size_t)e * NN + r];            // coalesced dword
            unsigned g  = *(const unsigned*)(Sb + (pk >> 16));   // ds_read_b32, byte off
            unsigned v2 = __builtin_amdgcn_perm(pk, pk, 0x01000100u);  // dup low16
            acc = __hfma2(*(__half2*)&v2, *(__half2*)&g, acc);   // v_pk_fma_f16
        }
        return *(unsigned*)&acc;
    };

    // Y1 = L_hat @ x ;  H = c0*x + c1*Y1
    unsigned A0 = gather(0, r0, len0);
    unsigned A1 = gather(0, r1, len1);
    S[1][r0] = A0;
    S[1][r1] = A1;
    float2 xf0 = h2f2(X0), xf1 = h2f2(X1);
    float2 yf0 = h2f2(A0), yf1 = h2f2(A1);
    float cA0 = cc_cm[r0], cB0 = cc_cm[NN + r0];
    float cA1 = cc_cm[r1], cB1 = cc_cm[NN + r1];
    float2 H0 = make_float2(cA0 * xf0.x + cB0 * yf0.x, cA0 * xf0.y + cB0 * yf0.y);
    float2 H1 = make_float2(cA1 * xf1.x + cB1 * yf1.x, cA1 * xf1.y + cB1 * yf1.y);

    int cur = 1;
    for (int k = 2; k <= K; ++k) {
        __syncthreads();
        unsigned G0 = gather(cur, r0, len0);
        unsigned G1 = gather(cur, r1, len1);
        int oth = cur ^ 1;
        float2 gf0 = h2f2(G0), gf1 = h2f2(G1);
        float2 pf0 = h2f2(S[oth][r0]), pf1 = h2f2(S[oth][r1]);
        float2 t0 = make_float2(2.f * gf0.x - pf0.x, 2.f * gf0.y - pf0.y);
        float2 t1 = make_float2(2.f * gf1.x - pf1.x, 2.f * gf1.y - pf1.y);
        __syncthreads();   // all reads of S[oth] done before overwrite
        S[oth][r0] = f2h2(t0.x, t0.y);
        S[oth][r1] = f2h2(t1.x, t1.y);
        float ck0 = cc_cm[k * NN + r0];
        float ck1 = cc_cm[k * NN + r1];
        H0.x += ck0 * t0.x; H0.y += ck0 * t0.y;
        H1.x += ck1 * t1.x; H1.y += ck1 * t1.y;
        cur = oth;
    }

    outT[(size_t)c0 * NN + r0]       = H0.x;   // coalesced dword stores
    outT[(size_t)(c0 + 1) * NN + r0] = H0.y;
    outT[(size_t)c0 * NN + r1]       = H1.x;
    outT[(size_t)(c0 + 1) * NN + r1] = H1.y;
}

// ---------------------------------------------------------------------------
// Kernel E: transpose outT[f][r] -> out[r][f].  Both directions coalesced.
// grid (NF/64, NN/64) = (8, 32), block 256.
// ---------------------------------------------------------------------------
__global__ __launch_bounds__(256) void xpose_out(const float* __restrict__ outT,
                                                 float* __restrict__ out) {
    __shared__ float tile[64][65];
    int f0 = blockIdx.x * 64;
    int r0 = blockIdx.y * 64;
    int tx = threadIdx.x & 63, ty = threadIdx.x >> 6;
#pragma unroll
    for (int i = 0; i < 16; ++i) {
        int ff = ty * 16 + i;
        tile[ff][tx] = outT[(size_t)(f0 + ff) * NN + r0 + tx];
    }
    __syncthreads();
#pragma unroll
    for (int i = 0; i < 16; ++i) {
        int rr = ty * 16 + i;
        out[(size_t)(r0 + rr) * NF + f0 + tx] = tile[tx][rr];
    }
}

// ---------------------------------------------------------------------------
extern "C" void kernel_launch(void* const* d_in, const int* in_sizes, int n_in,
                              void* d_out, int out_size, void* d_ws, size_t ws_size,
                              hipStream_t stream) {
    const float* x      = (const float*)d_in[0];   // [N,F]
    const float* P_n    = (const float*)d_in[1];   // [N,N]
    const float* t      = (const float*)d_in[2];   // [N]
    const float* eigmax = (const float*)d_in[3];   // [1]
    float* out = (float*)d_out;

    char* p = (char*)d_ws;
    auto carve = [&](size_t bytes) -> void* {
        void* r = (void*)p;
        p += (bytes + 255) & ~(size_t)255;
        return r;
    };
    float*          cc_cm  = (float*)         carve((size_t)(MCH + 1) * NN * sizeof(float));
    unsigned*       packed = (unsigned*)      carve((size_t)KMAX * NN * sizeof(unsigned));
    int*            lens   = (int*)           carve((size_t)NN * sizeof(int));
    float*          pmax   = (float*)         carve((size_t)256 * sizeof(float));
    int*            kslots = (int*)           carve((size_t)32 * sizeof(int));
    unsigned short* xT     = (unsigned short*)carve((size_t)NF * NN * sizeof(unsigned short));
    float*          outT   = (float*)         carve((size_t)NF * NN * sizeof(float));

    xpose_in<<<dim3(NN / 64, NF / 64), dim3(256), 0, stream>>>(x, xT, pmax);
    csr_kernel<<<dim3(NN), dim3(256), 0, stream>>>(P_n, eigmax, packed, lens);
    coeff_kernel<<<dim3(NN / 64), dim3(64), 0, stream>>>(t, eigmax, pmax, cc_cm, kslots, out);
    cheb_fused<<<dim3(NF / 2), dim3(1024), 0, stream>>>(xT, cc_cm, packed, lens, kslots, outT);
    xpose_out<<<dim3(NF / 64, NN / 64), dim3(256), 0, stream>>>(outT, out);
}